// Round 16
// baseline (142.584 us; speedup 1.0000x reference)
//
#include <hip/hip_runtime.h>

#define BATCH     256
#define INPUT_DIM 4096
#define SOMA      2048
#define BRANCHES  16
#define NDEND     32768
#define SAMPLE    32

#define THREADS   512
#define B_T       4                       // batch rows per tile (4 bf16 per b64)
#define NBT       4                       // tiles per block -> 16 rows/block
#define TILE_B    (INPUT_DIM * 8)         // 32 KiB LDS tile -> 4 blocks/CU

typedef unsigned int u32;
typedef float f32x2 __attribute__((ext_vector_type(2)));
typedef __attribute__((address_space(1))) const u32 gu32;
typedef __attribute__((address_space(3))) u32 lu32;

__device__ __forceinline__ void async_load16(const void* g, void* l) {
    __builtin_amdgcn_global_load_lds((const gu32*)g, (lu32*)l, 16, 0, 0);
}

__device__ __forceinline__ u32 bf16rne(float f) {   // round-to-nearest-even bf16
    u32 u = __float_as_uint(f);
    return (u + 0x7FFFu + ((u >> 16) & 1u)) >> 16;
}

// 16-lane sum via DPP (VALU pipe only, no LDS traffic)
__device__ __forceinline__ float dpp_red16(float v) {
    int x;
    x = __builtin_amdgcn_update_dpp(0, __float_as_int(v), 0xB1,  0xF, 0xF, true);
    v += __int_as_float(x);                         // xor1
    x = __builtin_amdgcn_update_dpp(0, __float_as_int(v), 0x4E,  0xF, 0xF, true);
    v += __int_as_float(x);                         // xor2
    x = __builtin_amdgcn_update_dpp(0, __float_as_int(v), 0x141, 0xF, 0xF, true);
    v += __int_as_float(x);                         // row_half_mirror
    x = __builtin_amdgcn_update_dpp(0, __float_as_int(v), 0x140, 0xF, 0xF, true);
    v += __int_as_float(x);                         // row_mirror
    return v;
}

// ---- pack x[256][4096] f32 -> xP[64 btile][4096 i][4 bb] bf16 (8B units) ----
#define TT 64
__global__ __launch_bounds__(256)
void pack_kernel(const float* __restrict__ x, u32* __restrict__ xP)
{
    __shared__ float ts[TT * (TT + 1)];             // ts[i_loc*65 + b_loc]
    const int j  = threadIdx.x;
    const int tx = j & 63;
    const int ty = j >> 6;
    const int gi = blockIdx.x * TT;
    const int gb = blockIdx.y * TT;

    #pragma unroll
    for (int r = 0; r < 16; ++r) {                  // read x coalesced along i
        const int b = ty + 4 * r;
        ts[tx * (TT + 1) + b] = x[(size_t)(gb + b) * INPUT_DIM + gi + tx];
    }
    __syncthreads();

    #pragma unroll
    for (int rep = 0; rep < 4; ++rep) {             // 1024 items of 8B
        const int idx   = rep * 256 + j;
        const int i_loc = idx & 63;                 // consecutive lanes -> coalesced
        const int bgr   = idx >> 6;                 // batch group 0..15 (4 rows each)
        const float* s  = &ts[i_loc * (TT + 1) + bgr * 4];
        uint2 q;
        q.x = bf16rne(s[0]) | (bf16rne(s[1]) << 16);
        q.y = bf16rne(s[2]) | (bf16rne(s[3]) << 16);
        ((uint2*)xP)[(size_t)(gb / 4 + bgr) * INPUT_DIM + gi + i_loc] = q;
    }
}

// ---------------- main fused kernel: 4 blocks/CU = 32 waves/CU ----------------
// 32KB LDS tile + ~50-reg live set (fits VGPR=64 cleanly, R8 precedent).
// Four independent blocks per CU interleave stage/barrier/gather phases.
__global__ __launch_bounds__(THREADS, 4)
void dendrite_kernel(const char* __restrict__ xP,   // [64][4096][4bb] bf16
                     const int*   __restrict__ didx,
                     const float* __restrict__ sw,
                     const float* __restrict__ sb,
                     const float* __restrict__ cw,
                     const float* __restrict__ somab,
                     float* __restrict__ soma_out,   // [BATCH][SOMA]
                     float* __restrict__ dend_out)   // [BATCH][NDEND]
{
    __shared__ char xs[TILE_B];                     // 32 KiB, single buffer

    const int t  = threadIdx.x;
    const int dc = blockIdx.x;                      // 64 chunks; XCD = dc%8
    const int bs = blockIdx.y;                      // 16 batch super-tiles
    const int d  = dc * THREADS + t;                // this thread's dendrite

    // ---- idx + bf16-packed weights ONCE into registers (32 regs) ----
    u32 off[SAMPLE / 2];
    u32 wpk[SAMPLE / 2];
    {
        const int4*   ip = (const int4*)  (didx + (size_t)d * SAMPLE);
        const float4* wp = (const float4*)(sw   + (size_t)d * SAMPLE);
        #pragma unroll
        for (int G = 0; G < SAMPLE / 4; ++G) {
            const int4   iv = ip[G];
            const float4 wv = wp[G];
            off[2*G]   = ((u32)iv.x << 3) | ((u32)iv.y << 19);  // byte off = i*8
            off[2*G+1] = ((u32)iv.z << 3) | ((u32)iv.w << 19);
            wpk[2*G]   = bf16rne(wv.x) | (bf16rne(wv.y) << 16);
            wpk[2*G+1] = bf16rne(wv.z) | (bf16rne(wv.w) << 16);
        }
    }
    const float bias = sb[d];
    const float cwv  = cw[d];
    const int   n    = d >> 4;
    const float sbi  = somab[n];
    const int   b00  = bs * (B_T * NBT);

    #pragma unroll 1
    for (int k = 0; k < NBT; ++k) {
        const int b0 = b00 + k * B_T;

        if (k > 0) __syncthreads();                 // previous tile's readers done

        // ---- stage tile k: 4 async 16B loads/thread, contiguous, zero VGPR ----
        {
            const char* tb = xP + (size_t)(bs * NBT + k) * TILE_B;
            #pragma unroll
            for (int r = 0; r < TILE_B / 16 / THREADS; ++r) {   // 4
                const int o = (r * THREADS + t) * 16;
                async_load16(tb + o, xs + o);
            }
        }
        __syncthreads();                            // implicit vmcnt(0): tile landed

        // ---- gather + unpack + packed FMA (regs + LDS only) ----
        const char* buf = (const char*)xs;
        f32x2 acc0 = {0.f,0.f}, acc1 = {0.f,0.f};
        #pragma unroll
        for (int g = 0; g < SAMPLE / 2; ++g) {
            const u32 pr  = off[g];
            const u32 wp2 = wpk[g];
            const uint2 q0 = *(const uint2*)(buf + (pr & 0xFFFFu));
            const uint2 q1 = *(const uint2*)(buf + (pr >> 16));
            const float w0s = __uint_as_float(wp2 << 16);
            const float w1s = __uint_as_float(wp2 & 0xFFFF0000u);
            const f32x2 w0 = {w0s, w0s};
            const f32x2 w1 = {w1s, w1s};
            f32x2 v;
            v = (f32x2){__uint_as_float(q0.x << 16), __uint_as_float(q0.x & 0xFFFF0000u)};
            acc0 += v * w0;
            v = (f32x2){__uint_as_float(q0.y << 16), __uint_as_float(q0.y & 0xFFFF0000u)};
            acc1 += v * w0;
            v = (f32x2){__uint_as_float(q1.x << 16), __uint_as_float(q1.x & 0xFFFF0000u)};
            acc0 += v * w1;
            v = (f32x2){__uint_as_float(q1.y << 16), __uint_as_float(q1.y & 0xFFFF0000u)};
            acc1 += v * w1;
        }

        // ---- inline epilogue: nt dend stores, DPP soma reduce ----
        const float a[B_T] = {acc0.x, acc0.y, acc1.x, acc1.y};
        #pragma unroll
        for (int bb = 0; bb < B_T; ++bb) {
            const float pre = a[bb] + bias;
            const float act = (pre >= 0.f) ? pre : 0.1f * pre;
            __builtin_nontemporal_store(act,
                &dend_out[(size_t)(b0 + bb) * NDEND + d]);       // coalesced
            const float s16 = dpp_red16(act * cwv);              // VALU-only
            if ((t & (BRANCHES - 1)) == 0) {
                const float pre2 = s16 + sbi;
                soma_out[(size_t)(b0 + bb) * SOMA + n] =
                    (pre2 >= 0.f) ? pre2 : 0.1f * pre2;
            }
        }
    }
}

extern "C" void kernel_launch(void* const* d_in, const int* in_sizes, int n_in,
                              void* d_out, int out_size, void* d_ws, size_t ws_size,
                              hipStream_t stream) {
    const float* x     = (const float*)d_in[0];
    const int*   didx  = (const int*)  d_in[1];
    const float* sw    = (const float*)d_in[2];
    const float* sb    = (const float*)d_in[3];
    const float* cw    = (const float*)d_in[4];
    const float* somab = (const float*)d_in[5];

    float* soma_out = (float*)d_out;                     // [256][2048]
    float* dend_out = soma_out + (size_t)BATCH * SOMA;   // [256][32768]
    u32*   xP       = (u32*)d_ws;                        // 2 MiB bf16 image (8B/i)

    dim3 pgrid(INPUT_DIM / TT, BATCH / TT);              // (64, 4)
    pack_kernel<<<pgrid, 256, 0, stream>>>(x, xP);

    // 1024 blocks of 512 thr, 32KB LDS each -> exactly 4 blocks/CU =
    // 32 waves/CU. XCD = dc%8 (idx/w + xP ~3MB L2-resident per XCD).
    dim3 grid(NDEND / THREADS, BATCH / (B_T * NBT));     // (64, 16)
    dendrite_kernel<<<grid, THREADS, 0, stream>>>(
        (const char*)xP, didx, sw, sb, cw, somab, soma_out, dend_out);
}